// Round 2
// baseline (165.353 us; speedup 1.0000x reference)
//
#include <hip/hip_runtime.h>
#include <math.h>

#define INV2PI 0.15915494309189535f  // 1/(2*pi)

// ---------------------------------------------------------------------------
// Kernel 1: sums.  Each wave owns one neuron n; lanes = batches (64 = B).
// For each d-chunk of 128: stage x transposed (x_s[b][dd], stride 129 ->
// conflict-free reads), stage invw' = INV2PI/(1+|W|) and bp' = B_p*INV2PI
// (computed once per (n,d), amortized over all 64 batches).
// Hot loop per element: fma -> fract -> v_cos + v_sin -> 2 acc adds.
// t is folded in AFTER the d-sum via the rotation identity:
//   sum cos(2pi*a + t) = cos(t)*A_c - sin(t)*A_s   (exact)
//   sum sin(2pi*a + t) = sin(t)*A_c + cos(t)*A_s
// Output: S2[n*64 + b] = (cos_sum, sin_sum)  (coalesced float2 store).
// ---------------------------------------------------------------------------
__global__ __launch_bounds__(256, 2) void k_sums(
    const float* __restrict__ x, const float* __restrict__ t,
    const float* __restrict__ W, const float* __restrict__ Bp,
    float2* __restrict__ S2)
{
    __shared__ float x_s[64][129];   // odd stride: bank = (lane+dd)%32, 2-way = free
    __shared__ float iw_s[4][128];
    __shared__ float bp_s[4][128];

    const int tid  = threadIdx.x;
    const int lane = tid & 63;                                   // = batch b
    const int wid  = __builtin_amdgcn_readfirstlane(tid >> 6);   // wave id 0..3
    const int nb   = blockIdx.x * 4;                             // neuron base

    float accC = 0.0f, accS = 0.0f;   // A_c, A_s (t not yet applied)

    const float4* x4 = reinterpret_cast<const float4*>(x);

    for (int c = 0; c < 8; ++c) {
        const int d0 = c * 128;

        // ---- stage x chunk, transposed: 64 b x 128 dd  (2048 float4s) ----
        #pragma unroll
        for (int i = 0; i < 8; ++i) {
            int f4 = tid + 256 * i;          // 0..2047
            int b  = f4 >> 5;                // 32 float4 per row-chunk
            int dq = f4 & 31;
            float4 v = x4[b * 256 + (d0 >> 2) + dq];
            x_s[b][dq * 4 + 0] = v.x;
            x_s[b][dq * 4 + 1] = v.y;
            x_s[b][dq * 4 + 2] = v.z;
            x_s[b][dq * 4 + 3] = v.w;
        }

        // ---- stage invw' and bp' for this block's 4 neurons ----
        {
            int nl  = tid >> 6;
            int dd2 = lane * 2;
            const float2* W2 = reinterpret_cast<const float2*>(W  + (size_t)(nb + nl) * 1024 + d0);
            const float2* B2 = reinterpret_cast<const float2*>(Bp + (size_t)(nb + nl) * 1024 + d0);
            float2 w2 = W2[lane];
            float2 b2 = B2[lane];
            iw_s[nl][dd2]     = INV2PI / (1.0f + fabsf(w2.x));
            iw_s[nl][dd2 + 1] = INV2PI / (1.0f + fabsf(w2.y));
            bp_s[nl][dd2]     = b2.x * INV2PI;
            bp_s[nl][dd2 + 1] = b2.y * INV2PI;
        }
        __syncthreads();

        // ---- hot loop: 128 dd, all 64 batches in lanes ----
        #pragma unroll 8
        for (int dd = 0; dd < 128; ++dd) {
            float xv = x_s[lane][dd];
            float a  = fmaf(xv, iw_s[wid][dd], bp_s[wid][dd]);   // revolutions
            float r  = __builtin_amdgcn_fractf(a);
            accC += __builtin_amdgcn_cosf(r);
            accS += __builtin_amdgcn_sinf(r);
        }
        __syncthreads();
    }

    // rotation by t (exact identity), once per (n, b)
    const float tv = t[lane];
    const float ct = cosf(tv), st = sinf(tv);
    const int n = nb + wid;
    S2[n * 64 + lane] = make_float2(ct * accC - st * accS,
                                    st * accC + ct * accS);
}

// ---------------------------------------------------------------------------
// Kernel 2: split-K GEMM.  out^T[d][b] = sum_n Pr[d][n]*c[n][b] + Pi[d][n]*s[n][b]
// grid = (64 d-tiles of 16, 8 k-chunks of 256).  Each wave: 4 d-rows, lanes=b.
// Pr/Pi rows are wave-uniform -> scalar loads; S2 loads coalesced float2.
// Writes f32 partials [s][d][b] (coalesced).
// ---------------------------------------------------------------------------
__global__ __launch_bounds__(256, 4) void k_gemm(
    const float2* __restrict__ S2, const float* __restrict__ Pr,
    const float* __restrict__ Pi, float* __restrict__ partial)
{
    const int lane = threadIdx.x & 63;
    const int wid  = __builtin_amdgcn_readfirstlane(threadIdx.x >> 6);
    const int d0   = blockIdx.x * 16 + wid * 4;
    const int k0   = blockIdx.y * 256;

    const float* pr = Pr + (size_t)d0 * 2048 + k0;
    const float* pi = Pi + (size_t)d0 * 2048 + k0;

    float a0 = 0.f, a1 = 0.f, a2 = 0.f, a3 = 0.f;

    for (int kk = 0; kk < 256; kk += 4) {
        float2 cs[4];
        #pragma unroll
        for (int i = 0; i < 4; ++i)
            cs[i] = S2[(size_t)(k0 + kk + i) * 64 + lane];
        #pragma unroll
        for (int i = 0; i < 4; ++i) {
            a0 += pr[kk + i]        * cs[i].x + pi[kk + i]        * cs[i].y;
            a1 += pr[2048 + kk + i] * cs[i].x + pi[2048 + kk + i] * cs[i].y;
            a2 += pr[4096 + kk + i] * cs[i].x + pi[4096 + kk + i] * cs[i].y;
            a3 += pr[6144 + kk + i] * cs[i].x + pi[6144 + kk + i] * cs[i].y;
        }
    }

    float* p = partial + ((size_t)blockIdx.y * 1024 + d0) * 64 + lane;
    p[0]   = a0;
    p[64]  = a1;
    p[128] = a2;
    p[192] = a3;
}

// ---------------------------------------------------------------------------
// Kernel 3: reduce 8 split-K partials + SiLU + transpose to out[b][d].
// grid = 16 (d-tiles of 64).  Coalesced reads (lane=b), LDS transpose,
// coalesced writes (lane=d).
// ---------------------------------------------------------------------------
__global__ __launch_bounds__(256, 4) void k_reduce_silu(
    const float* __restrict__ partial, float* __restrict__ out)
{
    __shared__ float T[64][65];
    const int lane = threadIdx.x & 63;
    const int rr   = threadIdx.x >> 6;
    const int dt   = blockIdx.x * 64;

    #pragma unroll
    for (int i = 0; i < 16; ++i) {
        int dd = rr + 4 * i;
        float s = 0.f;
        #pragma unroll
        for (int ss = 0; ss < 8; ++ss)
            s += partial[((size_t)ss * 1024 + dt + dd) * 64 + lane];
        float sig = 1.0f / (1.0f + __expf(-s));
        T[dd][lane] = s * sig;
    }
    __syncthreads();
    #pragma unroll
    for (int i = 0; i < 16; ++i) {
        int b = rr + 4 * i;
        out[(size_t)b * 1024 + dt + lane] = T[lane][b];
    }
}

// ---------------------------------------------------------------------------
extern "C" void kernel_launch(void* const* d_in, const int* in_sizes, int n_in,
                              void* d_out, int out_size, void* d_ws, size_t ws_size,
                              hipStream_t stream)
{
    const float* x  = (const float*)d_in[0];   // (64,1024)
    const float* t  = (const float*)d_in[1];   // (64,)
    const float* W  = (const float*)d_in[2];   // (2048,1024)
    const float* Bp = (const float*)d_in[3];   // (2048,1024)
    const float* Pr = (const float*)d_in[4];   // (1024,2048)
    const float* Pi = (const float*)d_in[5];   // (1024,2048)
    // d_in[6], d_in[7]: sin/cos LUT — superseded by hardware v_sin/v_cos
    // (lerp'd 4096-entry LUT deviates from true sin by <= 3e-7; propagated
    //  output error ~0.03 vs threshold 27.8)

    float*  out     = (float*)d_out;                       // (64,1024) f32
    float2* S2      = (float2*)d_ws;                       // 2048*64 float2 = 1 MB
    float*  partial = (float*)((char*)d_ws + (1 << 20));   // 8*1024*64 f32 = 2 MB

    k_sums<<<512, 256, 0, stream>>>(x, t, W, Bp, S2);
    k_gemm<<<dim3(64, 8), 256, 0, stream>>>(S2, Pr, Pi, partial);
    k_reduce_silu<<<16, 256, 0, stream>>>(partial, out);
}